// Round 3
// baseline (82.120 us; speedup 1.0000x reference)
//
#include <hip/hip_runtime.h>

#define MB   2048   // model batches
#define NP   8192   // num points (scan length)
#define NF   8      // number of functions
#define RM   51     // removed leading iterations
#define NCH  64     // chunks per batch
#define CH   128    // NP / NCH, steps per chunk

// ws layout: maps (2x float4 per (c,b)) = 4 MB, then pe (float2 per (c,b)) = 1 MB

// ---------------- Phase 1: per-chunk affine composition (pair-coded) ----------------
// tile row stride 35 (odd): step-loop b32 reads are 2-way (free); staging b32
// writes ~2-way. Pair tables are SoA float[64]: random-e reads <=2-way.
__global__ __launch_bounds__(256) void ifs_phase1(
    const int* __restrict__ idxg, const float* __restrict__ W,
    const float* __restrict__ B, float4* __restrict__ maps)
{
    __shared__ int tile[256][35];                  // 32 pair-codes per row + pad
    __shared__ float P00[64], P01[64], P10[64], P11[64], Q0[64], Q1[64];
    const int tid = threadIdx.x;
    if (tid < 64) {
        const int fb = tid & 7;   // earlier step's function
        const int fa = tid >> 3;  // later step's function
        const float wa00 = W[fa*4+0], wa01 = W[fa*4+1], wa10 = W[fa*4+2], wa11 = W[fa*4+3];
        const float wb00 = W[fb*4+0], wb01 = W[fb*4+1], wb10 = W[fb*4+2], wb11 = W[fb*4+3];
        P00[tid] = wa00*wb00 + wa01*wb10;  P01[tid] = wa00*wb01 + wa01*wb11;
        P10[tid] = wa10*wb00 + wa11*wb10;  P11[tid] = wa10*wb01 + wa11*wb11;
        Q0[tid]  = wa00*B[fb*2+0] + wa01*B[fb*2+1] + B[fa*2+0];
        Q1[tid]  = wa10*B[fb*2+0] + wa11*B[fb*2+1] + B[fa*2+1];
    }

    const int c   = blockIdx.x >> 3;
    const int b0  = (blockIdx.x & 7) << 8;
    const int x16 = tid & 15, yy = tid >> 4;

    float a00 = 1.f, a01 = 0.f, a10 = 0.f, a11 = 1.f, c0 = 0.f, c1 = 0.f;

    for (int seg = 0; seg < 2; ++seg) {            // 2 x 64 original steps
        const int tb = c * CH + seg * 64;
        // coalesced: 16 lanes x int4 = one row's 64 ints (256B); 4 rows/wave-instr
        #pragma unroll
        for (int p = 0; p < 16; ++p) {
            const int row = yy + p * 16;
            const int4 v = *(const int4*)(idxg + (size_t)(b0 + row) * NP + tb + x16 * 4);
            tile[row][x16*2+0] = v.y * 8 + v.x;    // pair-code: later*8 + earlier
            tile[row][x16*2+1] = v.w * 8 + v.z;
        }
        __syncthreads();
        #pragma unroll
        for (int j = 0; j < 32; ++j) {
            const int e = tile[tid][j];
            const float p00 = P00[e], p01 = P01[e], p10 = P10[e], p11 = P11[e];
            const float q0 = Q0[e], q1 = Q1[e];
            const float na00 = p00*a00 + p01*a10;
            const float na01 = p00*a01 + p01*a11;
            const float na10 = p10*a00 + p11*a10;
            const float na11 = p10*a01 + p11*a11;
            const float nc0  = p00*c0  + p01*c1 + q0;
            const float nc1  = p10*c0  + p11*c1 + q1;
            a00 = na00; a01 = na01; a10 = na10; a11 = na11; c0 = nc0; c1 = nc1;
        }
        __syncthreads();
    }
    const size_t n = ((size_t)c * MB + b0 + tid) * 2;
    maps[n]     = make_float4(a00, a01, a10, a11);
    maps[n + 1] = make_float4(c0,  c1,  0.f, 0.f);
}

// ---------------- Phase 2: sequential scan over chunk maps (8-deep prefetch) ----------------
__global__ __launch_bounds__(256) void ifs_phase2(
    const float2* __restrict__ point, const float4* __restrict__ maps,
    float2* __restrict__ pe)
{
    const int b = blockIdx.x * 256 + threadIdx.x;
    float2 p = point[b];
    float4 lo[8], hi[8], nlo[8], nhi[8];
    #pragma unroll
    for (int k = 0; k < 8; ++k) {
        lo[k] = maps[((size_t)k * MB + b) * 2];
        hi[k] = maps[((size_t)k * MB + b) * 2 + 1];
    }
    for (int g = 0; g < 8; ++g) {
        if (g < 7) {
            #pragma unroll
            for (int k = 0; k < 8; ++k) {
                nlo[k] = maps[((size_t)((g + 1) * 8 + k) * MB + b) * 2];
                nhi[k] = maps[((size_t)((g + 1) * 8 + k) * MB + b) * 2 + 1];
            }
        }
        #pragma unroll
        for (int k = 0; k < 8; ++k) {
            pe[(size_t)(g * 8 + k) * MB + b] = p;
            const float nx = lo[k].x * p.x + lo[k].y * p.y + hi[k].x;
            const float ny = lo[k].z * p.x + lo[k].w * p.y + hi[k].y;
            p.x = nx; p.y = ny;
        }
        #pragma unroll
        for (int k = 0; k < 8; ++k) { lo[k] = nlo[k]; hi[k] = nhi[k]; }
    }
}

// ---------------- Phase 3: replay chunks, write outputs ----------------
// tile row stride 36: 16B-aligned rows, b128 reads quad-striped (tid%8) ->
// conflict-free; 1 b128 per 4 steps. Tables 8x16B: 8 addrs = 8 distinct
// bank-quads -> conflict-free broadcast.
template <bool CHECK>
__device__ __forceinline__ void phase3_step(
    int f, const float4* tA, const float4* tB, float2& p, float*& o, int t_loc)
{
    const float4 w  = tA[f];
    const float4 bb = tB[f];
    const float nx = w.x * p.x + w.y * p.y + bb.x;
    const float ny = w.z * p.x + w.w * p.y + bb.y;
    p.x = nx; p.y = ny;
    if (!CHECK || t_loc >= RM) {                   // folds: t_loc is unroll-const
        __builtin_nontemporal_store(p.x,  o + 0);
        __builtin_nontemporal_store(p.y,  o + 1);
        __builtin_nontemporal_store(bb.z, o + 2);
    }
    o += MB * 3;
}

template <bool CHECK>
__global__ __launch_bounds__(256) void ifs_phase3(
    const int* __restrict__ idxg, const float* __restrict__ W,
    const float* __restrict__ B, const float* __restrict__ OPS,
    const float2* __restrict__ pe, float* __restrict__ out)
{
    __shared__ int tile[256][36];
    __shared__ __align__(16) float4 tA[NF];        // {w00,w01,w10,w11}
    __shared__ __align__(16) float4 tB[NF];        // {b0,b1,op,0}
    const int tid = threadIdx.x;
    if (tid < NF) {
        tA[tid] = make_float4(W[tid*4+0], W[tid*4+1], W[tid*4+2], W[tid*4+3]);
        tB[tid] = make_float4(B[tid*2+0], B[tid*2+1], OPS[tid], 0.f);
    }

    const int c  = CHECK ? 0 : (blockIdx.x >> 3) + 1;
    const int b0 = (blockIdx.x & 7) << 8;
    const int b  = b0 + tid;
    const int x4 = tid & 7, yy = tid >> 3;

    float2 p = pe[(size_t)c * MB + b];
    float* o = out + ((long long)c * CH - RM) * (MB * 3) + (long long)b * 3;

    for (int seg = 0; seg < 4; ++seg) {            // 4 x 32 steps
        const int tb = c * CH + seg * 32;
        #pragma unroll
        for (int p8 = 0; p8 < 8; ++p8) {
            const int row = yy + p8 * 32;
            *(int4*)&tile[row][x4*4] = *(const int4*)(idxg + (size_t)(b0 + row) * NP + tb + x4 * 4);
        }
        __syncthreads();
        #pragma unroll
        for (int g = 0; g < 8; ++g) {
            const int4 f4 = *(const int4*)&tile[tid][g*4];
            const int base = seg * 32 + g * 4;
            phase3_step<CHECK>(f4.x, tA, tB, p, o, base + 0);
            phase3_step<CHECK>(f4.y, tA, tB, p, o, base + 1);
            phase3_step<CHECK>(f4.z, tA, tB, p, o, base + 2);
            phase3_step<CHECK>(f4.w, tA, tB, p, o, base + 3);
        }
        __syncthreads();
    }
}

extern "C" void kernel_launch(void* const* d_in, const int* in_sizes, int n_in,
                              void* d_out, int out_size, void* d_ws, size_t ws_size,
                              hipStream_t stream) {
    const float* point = (const float*)d_in[0];  // [2048,2,1]
    const float* W     = (const float*)d_in[1];  // [8,2,2]
    const float* B     = (const float*)d_in[2];  // [8,2,1]
    const float* OPS   = (const float*)d_in[3];  // [8]
    const int*   idx   = (const int*)  d_in[4];  // [2048,8192]
    float*       out   = (float*)d_out;          // [(8192-51)*2048, 3]

    float*  ws   = (float*)d_ws;
    float4* maps = (float4*)ws;                               // 4 MB
    float2* pe   = (float2*)(ws + (size_t)NCH * MB * 8);      // 1 MB

    ifs_phase1<<<NCH * (MB / 256), 256, 0, stream>>>(idx, W, B, maps);
    ifs_phase2<<<MB / 256, 256, 0, stream>>>((const float2*)point, maps, pe);
    ifs_phase3<true ><<<1 * (MB / 256), 256, 0, stream>>>(idx, W, B, OPS, pe, out);
    ifs_phase3<false><<<(NCH - 1) * (MB / 256), 256, 0, stream>>>(idx, W, B, OPS, pe, out);
}

// Round 5
// 70.779 us; speedup vs baseline: 1.1602x; 1.1602x over previous
//
#include <hip/hip_runtime.h>

#define MB   2048   // model batches
#define NP   8192   // num points (scan length)
#define NF   8      // number of functions
#define RM   51     // removed leading iterations
#define NCH  64     // chunks per batch
#define CH   128    // NP / NCH, steps per chunk

typedef float f32x4 __attribute__((ext_vector_type(4)));  // clang-native: nt-store OK

// ws layout: maps (2x float4 per (c,b)) = 4 MB, then pe (float2 per (c,b)) = 1 MB

// ---------------- Phase 1: per-chunk affine composition ----------------
// Round-1 structure: LDS idx tile (coalesced staging), 8-entry float4 tables
// (8 addrs = 32 banks exactly -> conflict-free broadcast b128 reads).
__global__ __launch_bounds__(256) void ifs_phase1(
    const int* __restrict__ idxg, const float* __restrict__ W,
    const float* __restrict__ B, float4* __restrict__ maps)
{
    __shared__ int tile[256][33];               // stride 33: (tid+s)%32 -> 2-way free
    __shared__ __align__(16) float tbl[NF][8];  // {w00,w01,w10,w11,b0,b1,0,0}
    const int tid = threadIdx.x;
    if (tid < NF) {
        tbl[tid][0] = W[tid*4+0]; tbl[tid][1] = W[tid*4+1];
        tbl[tid][2] = W[tid*4+2]; tbl[tid][3] = W[tid*4+3];
        tbl[tid][4] = B[tid*2+0]; tbl[tid][5] = B[tid*2+1];
        tbl[tid][6] = 0.f;        tbl[tid][7] = 0.f;
    }
    const int c  = blockIdx.x >> 3;
    const int b0 = (blockIdx.x & 7) << 8;
    const int x4 = tid & 7, yy = tid >> 3;

    float a00 = 1.f, a01 = 0.f, a10 = 0.f, a11 = 1.f, c0 = 0.f, c1 = 0.f;

    for (int seg = 0; seg < 4; ++seg) {
        const int tb = c * CH + seg * 32;
        #pragma unroll
        for (int p = 0; p < 8; ++p) {
            const int row = yy + p * 32;
            const int4 v = *(const int4*)(idxg + (size_t)(b0 + row) * NP + tb + x4 * 4);
            tile[row][x4*4+0] = v.x; tile[row][x4*4+1] = v.y;
            tile[row][x4*4+2] = v.z; tile[row][x4*4+3] = v.w;
        }
        __syncthreads();
        #pragma unroll
        for (int s = 0; s < 32; ++s) {
            const int f = tile[tid][s];
            const float4 wl = *(const float4*)&tbl[f][0];
            const float4 wh = *(const float4*)&tbl[f][4];
            const float na00 = wl.x*a00 + wl.y*a10;
            const float na01 = wl.x*a01 + wl.y*a11;
            const float na10 = wl.z*a00 + wl.w*a10;
            const float na11 = wl.z*a01 + wl.w*a11;
            const float nc0  = wl.x*c0  + wl.y*c1 + wh.x;
            const float nc1  = wl.z*c0  + wl.w*c1 + wh.y;
            a00 = na00; a01 = na01; a10 = na10; a11 = na11; c0 = nc0; c1 = nc1;
        }
        __syncthreads();
    }
    const size_t n = ((size_t)c * MB + b0 + tid) * 2;
    maps[n]     = make_float4(a00, a01, a10, a11);
    maps[n + 1] = make_float4(c0,  c1,  0.f, 0.f);
}

// ---------------- Phase 2: sequential scan over chunk maps (8-deep prefetch) ----------------
__global__ __launch_bounds__(64) void ifs_phase2(
    const float2* __restrict__ point, const float4* __restrict__ maps,
    float2* __restrict__ pe)
{
    const int b = blockIdx.x * 64 + threadIdx.x;   // 32 blocks -> 32 CUs
    float2 p = point[b];
    float4 lo[8], hi[8], nlo[8], nhi[8];
    #pragma unroll
    for (int k = 0; k < 8; ++k) {
        lo[k] = maps[((size_t)k * MB + b) * 2];
        hi[k] = maps[((size_t)k * MB + b) * 2 + 1];
    }
    for (int g = 0; g < 8; ++g) {
        if (g < 7) {
            #pragma unroll
            for (int k = 0; k < 8; ++k) {
                nlo[k] = maps[((size_t)((g + 1) * 8 + k) * MB + b) * 2];
                nhi[k] = maps[((size_t)((g + 1) * 8 + k) * MB + b) * 2 + 1];
            }
        }
        #pragma unroll
        for (int k = 0; k < 8; ++k) {
            pe[(size_t)(g * 8 + k) * MB + b] = p;
            const float nx = lo[k].x * p.x + lo[k].y * p.y + hi[k].x;
            const float ny = lo[k].z * p.x + lo[k].w * p.y + hi[k].y;
            p.x = nx; p.y = ny;
        }
        #pragma unroll
        for (int k = 0; k < 8; ++k) { lo[k] = nlo[k]; hi[k] = nhi[k]; }
    }
}

// ---------------- Phase 3: replay chunks, transpose-coalesced output ----------------
// Per 4-step group: compute 4 steps into ping-pong LDS (all patterns <=2-way
// aliasing = free), barrier, 3 fully-coalesced f32x4 nt-stores per thread.
template <bool CHECK>
__device__ __forceinline__ void phase3_body(
    const int* __restrict__ idxg, const float4* tA, const float4* tB,
    float (*sbuf)[4][256][3], int (*tile)[36],
    int c, int b0, int tid, const float2* __restrict__ pe,
    float* __restrict__ out)
{
    const int x4 = tid & 7, yy = tid >> 3;
    float2 p = pe[(size_t)c * MB + b0 + tid];

    // output-float4 decomposition: float4 k of this thread covers flat words
    // w=4*(tid+256k) of the 4x256x3-word group tile; step s=w/768, col r=w%768
    int s_[3], r_[3];
    #pragma unroll
    for (int k = 0; k < 3; ++k) {
        const int w = 4 * (tid + 256 * k);
        s_[k] = w / 768;
        r_[k] = w - s_[k] * 768;
    }
    long long off[3];
    #pragma unroll
    for (int k = 0; k < 3; ++k)
        off[k] = (long long)(c * CH + s_[k] - RM) * (MB * 3) + b0 * 3 + r_[k];

    int gg = 0;
    for (int seg = 0; seg < 4; ++seg) {
        const int tb = c * CH + seg * 32;
        #pragma unroll
        for (int p8 = 0; p8 < 8; ++p8) {
            const int row = yy + p8 * 32;
            *(int4*)&tile[row][x4*4] = *(const int4*)(idxg + (size_t)(b0 + row) * NP + tb + x4 * 4);
        }
        __syncthreads();
        #pragma unroll
        for (int g = 0; g < 8; ++g, ++gg) {
            const int buf = gg & 1;
            const int4 f4 = *(const int4*)&tile[tid][g*4];
            const int fs[4] = {f4.x, f4.y, f4.z, f4.w};
            #pragma unroll
            for (int s = 0; s < 4; ++s) {
                const float4 w  = tA[fs[s]];
                const float4 bb = tB[fs[s]];
                const float nx = w.x * p.x + w.y * p.y + bb.x;
                const float ny = w.z * p.x + w.w * p.y + bb.y;
                p.x = nx; p.y = ny;
                sbuf[buf][s][tid][0] = p.x;
                sbuf[buf][s][tid][1] = p.y;
                sbuf[buf][s][tid][2] = bb.z;
            }
            __syncthreads();
            const int t0 = seg * 32 + g * 4;   // chunk-local time of tile row 0
            const float* flat = &sbuf[buf][0][0][0];
            #pragma unroll
            for (int k = 0; k < 3; ++k) {
                if (!CHECK || (t0 + s_[k]) >= RM) {
                    const f32x4 v = *(const f32x4*)(flat + 4 * (tid + 256 * k));
                    __builtin_nontemporal_store(v, (f32x4*)(out + off[k]));
                }
                off[k] += 4LL * (MB * 3);
            }
        }
        __syncthreads();
    }
}

template <bool DUMMY>
__global__ __launch_bounds__(256) void ifs_phase3(
    const int* __restrict__ idxg, const float* __restrict__ W,
    const float* __restrict__ B, const float* __restrict__ OPS,
    const float2* __restrict__ pe, float* __restrict__ out)
{
    __shared__ int tile[256][36];                 // b128 reads quad-striped: 2-way free
    __shared__ __align__(16) float sbuf[2][4][256][3];  // ping-pong transpose (24 KB)
    __shared__ __align__(16) float4 tA[NF];       // {w00,w01,w10,w11} conflict-free
    __shared__ __align__(16) float4 tB[NF];       // {b0,b1,op,0}      conflict-free
    const int tid = threadIdx.x;
    if (tid < NF) {
        tA[tid] = make_float4(W[tid*4+0], W[tid*4+1], W[tid*4+2], W[tid*4+3]);
        tB[tid] = make_float4(B[tid*2+0], B[tid*2+1], OPS[tid], 0.f);
    }

    const int c  = blockIdx.x >> 3;
    const int b0 = (blockIdx.x & 7) << 8;

    if (c == 0) phase3_body<true >(idxg, tA, tB, sbuf, tile, c, b0, tid, pe, out);
    else        phase3_body<false>(idxg, tA, tB, sbuf, tile, c, b0, tid, pe, out);
}

extern "C" void kernel_launch(void* const* d_in, const int* in_sizes, int n_in,
                              void* d_out, int out_size, void* d_ws, size_t ws_size,
                              hipStream_t stream) {
    const float* point = (const float*)d_in[0];  // [2048,2,1]
    const float* W     = (const float*)d_in[1];  // [8,2,2]
    const float* B     = (const float*)d_in[2];  // [8,2,1]
    const float* OPS   = (const float*)d_in[3];  // [8]
    const int*   idx   = (const int*)  d_in[4];  // [2048,8192]
    float*       out   = (float*)d_out;          // [(8192-51)*2048, 3]

    float*  ws   = (float*)d_ws;
    float4* maps = (float4*)ws;                               // 4 MB
    float2* pe   = (float2*)(ws + (size_t)NCH * MB * 8);      // 1 MB

    ifs_phase1<<<NCH * (MB / 256), 256, 0, stream>>>(idx, W, B, maps);
    ifs_phase2<<<MB / 64, 64, 0, stream>>>((const float2*)point, maps, pe);
    ifs_phase3<false><<<NCH * (MB / 256), 256, 0, stream>>>(idx, W, B, OPS, pe, out);
}